// Round 5
// baseline (391.453 us; speedup 1.0000x reference)
//
#include <hip/hip_runtime.h>
#include <hip/hip_bf16.h>
#include <stdint.h>
#include <math.h>

#define T_DIM 4096   // rows of x2 (2*2048)
#define IN_DIM 4096  // inner dim
#define N_DIM 4096   // output dim
#define GROUPS 32    // row-groups for stats partial reduction
#define ROWS_PG (T_DIM / GROUPS)   // 128

typedef __attribute__((ext_vector_type(8))) short short8;
typedef __attribute__((ext_vector_type(4))) short short4v;
typedef __attribute__((ext_vector_type(4))) float f32x4;

__device__ __forceinline__ uint32_t umin32(uint32_t a, uint32_t b){ return a < b ? a : b; }
__device__ __forceinline__ uint32_t umax32(uint32_t a, uint32_t b){ return a > b ? a : b; }

__device__ __forceinline__ unsigned short bf16bits(float f) {
  __hip_bfloat16 h = __float2bfloat16(f);
  return *reinterpret_cast<unsigned short*>(&h);
}

// monotone float->uint key (ascending key order == ascending float order)
__device__ __forceinline__ uint32_t f2key(float f) {
  uint32_t u = __float_as_uint(f);
  return (u & 0x80000000u) ? ~u : (u | 0x80000000u);
}
__device__ __forceinline__ float key2f(uint32_t k) {
  uint32_t u = (k & 0x80000000u) ? (k ^ 0x80000000u) : ~k;
  return __uint_as_float(u);
}

// maintain sorted bottom-4 (b0<=b1<=b2<=b3)
__device__ __forceinline__ void ins_bot(uint32_t& b0, uint32_t& b1, uint32_t& b2, uint32_t& b3, uint32_t v) {
  b3 = umin32(b3, v);
  uint32_t lo, hi;
  lo = umin32(b2, b3); hi = umax32(b2, b3); b2 = lo; b3 = hi;
  lo = umin32(b1, b2); hi = umax32(b1, b2); b1 = lo; b2 = hi;
  lo = umin32(b0, b1); hi = umax32(b0, b1); b0 = lo; b1 = hi;
}
// maintain sorted top-4 (t0>=t1>=t2>=t3)
__device__ __forceinline__ void ins_top(uint32_t& t0, uint32_t& t1, uint32_t& t2, uint32_t& t3, uint32_t v) {
  t3 = umax32(t3, v);
  uint32_t lo, hi;
  hi = umax32(t2, t3); lo = umin32(t2, t3); t2 = hi; t3 = lo;
  hi = umax32(t1, t2); lo = umin32(t1, t2); t1 = hi; t2 = lo;
  hi = umax32(t0, t1); lo = umin32(t0, t1); t0 = hi; t1 = lo;
}

// ---------------------------------------------------------------------------
// K1a: partial per-column bottom-4/top-4 over a 128-row group.
// Thread owns one column -> every global load is wave-coalesced (256B/wave).
// ---------------------------------------------------------------------------
__global__ __launch_bounds__(256) void stats_part(const float* __restrict__ x,
                                                  uint32_t* __restrict__ cand) {
  const int c = blockIdx.x * 256 + threadIdx.x;
  const int g = blockIdx.y;
  const float* xp = x + (size_t)g * ROWS_PG * IN_DIM + c;

  uint32_t b0 = 0xFFFFFFFFu, b1 = 0xFFFFFFFFu, b2 = 0xFFFFFFFFu, b3 = 0xFFFFFFFFu;
  uint32_t t0 = 0u, t1 = 0u, t2 = 0u, t3 = 0u;
  #pragma unroll 8
  for (int r = 0; r < ROWS_PG; ++r) {
    const uint32_t v = f2key(xp[(size_t)r * IN_DIM]);
    ins_bot(b0, b1, b2, b3, v);
    ins_top(t0, t1, t2, t3, v);
  }
  const size_t base = (size_t)g * IN_DIM + c;
  const size_t stride = (size_t)GROUPS * IN_DIM;
  cand[0 * stride + base] = b0;
  cand[1 * stride + base] = b1;
  cand[2 * stride + base] = b2;
  cand[3 * stride + base] = b3;
  cand[4 * stride + base] = t0;
  cand[5 * stride + base] = t1;
  cand[6 * stride + base] = t2;
  cand[7 * stride + base] = t3;
}

// ---------------------------------------------------------------------------
// K1b: merge GROUPS candidate quadruples per column -> stats.
// s[2]=b2, s[3]=b3, s[4092]=t3, s[4093]=t2; median is dead code (always
// strictly inside (lower,upper)), so masked min/max = s[3]/s[4092] exactly.
// ---------------------------------------------------------------------------
__global__ __launch_bounds__(256) void stats_merge(const uint32_t* __restrict__ cand,
                                                   float* __restrict__ stats) {
  const int c = blockIdx.x * 256 + threadIdx.x;
  const size_t stride = (size_t)GROUPS * IN_DIM;

  uint32_t b0 = 0xFFFFFFFFu, b1 = 0xFFFFFFFFu, b2 = 0xFFFFFFFFu, b3 = 0xFFFFFFFFu;
  uint32_t t0 = 0u, t1 = 0u, t2 = 0u, t3 = 0u;
  #pragma unroll 4
  for (int g = 0; g < GROUPS; ++g) {
    const size_t base = (size_t)g * IN_DIM + c;
    const uint32_t cb0 = cand[0 * stride + base];
    const uint32_t cb1 = cand[1 * stride + base];
    const uint32_t cb2 = cand[2 * stride + base];
    const uint32_t cb3 = cand[3 * stride + base];
    const uint32_t ct0 = cand[4 * stride + base];
    const uint32_t ct1 = cand[5 * stride + base];
    const uint32_t ct2 = cand[6 * stride + base];
    const uint32_t ct3 = cand[7 * stride + base];
    ins_bot(b0, b1, b2, b3, cb0); ins_bot(b0, b1, b2, b3, cb1);
    ins_bot(b0, b1, b2, b3, cb2); ins_bot(b0, b1, b2, b3, cb3);
    ins_top(t0, t1, t2, t3, ct0); ins_top(t0, t1, t2, t3, ct1);
    ins_top(t0, t1, t2, t3, ct2); ins_top(t0, t1, t2, t3, ct3);
  }

  const float s2 = key2f(b2), s3 = key2f(b3);
  const float s4092 = key2f(t3), s4093 = key2f(t2);
  const float lowerF = s2 + 0.0475f * (s3 - s2);          // pos 0.0005*4095
  const float upperF = s4092 + 0.9525f * (s4093 - s4092); // pos 0.9995*4095
  const float minval = s3, maxval = s4092;                // exact masked min/max
  stats[0 * IN_DIM + c] = lowerF;
  stats[1 * IN_DIM + c] = upperF;
  stats[2 * IN_DIM + c] = (maxval + minval) * 0.5f;
  stats[3 * IN_DIM + c] = (maxval - minval) * 0.5f;
}

// ---------------------------------------------------------------------------
// K2: quantize x -> q (bf16). Row-major vectorized: float4 in, 4x bf16 out.
// ---------------------------------------------------------------------------
__global__ __launch_bounds__(256) void quant_kernel(const float* __restrict__ x,
                                                    const float* __restrict__ stats,
                                                    const float* __restrict__ lut,
                                                    __hip_bfloat16* __restrict__ q) {
  const size_t e0 = ((size_t)blockIdx.x * 256 + threadIdx.x) * 4;
  const int c = (int)(e0 & (IN_DIM - 1));   // 4 consecutive cols, no row wrap

  float lutv[16];
  #pragma unroll
  for (int j = 0; j < 16; ++j) lutv[j] = lut[j];
  float mid[15];
  #pragma unroll
  for (int j = 0; j < 15; ++j) mid[j] = 0.5f * (lutv[j] + lutv[j + 1]);

  const float4 xv4  = *reinterpret_cast<const float4*>(x + e0);
  const float4 lo4  = *reinterpret_cast<const float4*>(stats + 0 * IN_DIM + c);
  const float4 hi4  = *reinterpret_cast<const float4*>(stats + 1 * IN_DIM + c);
  const float4 off4 = *reinterpret_cast<const float4*>(stats + 2 * IN_DIM + c);
  const float4 rng4 = *reinterpret_cast<const float4*>(stats + 3 * IN_DIM + c);

  const float xs[4]  = {xv4.x, xv4.y, xv4.z, xv4.w};
  const float los[4] = {lo4.x, lo4.y, lo4.z, lo4.w};
  const float his[4] = {hi4.x, hi4.y, hi4.z, hi4.w};
  const float ofs[4] = {off4.x, off4.y, off4.z, off4.w};
  const float rgs[4] = {rng4.x, rng4.y, rng4.z, rng4.w};

  short4v outv;
  #pragma unroll
  for (int j = 0; j < 4; ++j) {
    const float xv = xs[j];
    const bool msk = (xv <= los[j]) || (xv >= his[j]);
    const float xc = xv - ofs[j];
    const float s = xc / rgs[j];
    float p = lutv[0];
    #pragma unroll
    for (int j2 = 0; j2 < 15; ++j2) p = (s > mid[j2]) ? lutv[j2 + 1] : p;
    float qv = msk ? (xc + ofs[j]) : (p * rgs[j] + ofs[j]);
    if (!isfinite(qv)) qv = 0.0f;
    outv[j] = (short)bf16bits(qv);
  }
  *reinterpret_cast<short4v*>((short*)q + e0) = outv;   // 8 B aligned store
}

// ---------------------------------------------------------------------------
// K2b: W (K x N, f32) -> Wt (N x K, bf16). float4 loads, bf16 LDS tile
// (padded: 2-way banks only), 8 B vector stores.
// ---------------------------------------------------------------------------
__global__ __launch_bounds__(256) void wt_kernel(const float* __restrict__ wsrc,
                                                 __hip_bfloat16* __restrict__ wt) {
  __shared__ unsigned short tile[64][68];  // bf16, +4 pad keeps 8B-aligned rows
  const int n0 = blockIdx.x * 64, k0 = blockIdx.y * 64;
  const int lr = threadIdx.x >> 4;   // 0..15
  const int lc = threadIdx.x & 15;   // 0..15

  #pragma unroll
  for (int it = 0; it < 4; ++it) {
    const int krow = it * 16 + lr;
    const float4 v = *reinterpret_cast<const float4*>(wsrc + (size_t)(k0 + krow) * N_DIM + n0 + lc * 4);
    short4v b;
    b[0] = (short)bf16bits(v.x);
    b[1] = (short)bf16bits(v.y);
    b[2] = (short)bf16bits(v.z);
    b[3] = (short)bf16bits(v.w);
    *reinterpret_cast<short4v*>(&tile[krow][lc * 4]) = b;
  }
  __syncthreads();
  #pragma unroll
  for (int it = 0; it < 4; ++it) {
    const int nrow = it * 16 + lr;
    short4v o;
    #pragma unroll
    for (int i = 0; i < 4; ++i) o[i] = (short)tile[lc * 4 + i][nrow];
    *reinterpret_cast<short4v*>((short*)wt + (size_t)(n0 + nrow) * IN_DIM + k0 + lc * 4) = o;
  }
}

// ---------------------------------------------------------------------------
// K3: C = q(M x K) @ Wt^T   (Wt is N x K), bf16 MFMA 16x16x32, 128x128 tile.
// BK=64: same single-buffer 2-barrier sync semantics as before, but half the
// barrier-drain events (64 K-tiles instead of 128). LDS 32 KiB.
// ---------------------------------------------------------------------------
__global__ __launch_bounds__(256) void gemm_kernel(const __hip_bfloat16* __restrict__ A,
                                                   const __hip_bfloat16* __restrict__ Bt,
                                                   float* __restrict__ C) {
  constexpr int BK = 64, K = IN_DIM, N = N_DIM;
  __shared__ short sA[128 * BK];  // [m][k] 16 KiB
  __shared__ short sB[128 * BK];  // [n][k] 16 KiB
  const int tid = threadIdx.x, lane = tid & 63, w = tid >> 6;
  const int m0 = blockIdx.y * 128, n0 = blockIdx.x * 128;
  const int wm = (w >> 1) * 64, wn = (w & 1) * 64;

  f32x4 acc[4][4] = {};

  for (int k0 = 0; k0 < K; k0 += BK) {
    // stage: 8192 shorts per buffer; wave w owns [w*2048, (w+1)*2048),
    // 4 rounds x (64 lanes x 16B). LDS dest = wave-uniform base (+lane*16 HW).
    #pragma unroll
    for (int i = 0; i < 4; ++i) {
      const int ebase = w * 2048 + i * 512;      // short offset, wave-uniform
      const int e = ebase + lane * 8;
      const int row = e >> 6, kk = e & 63;
      __builtin_amdgcn_global_load_lds(
          (const __attribute__((address_space(1))) void*)(A + (size_t)(m0 + row) * K + k0 + kk),
          (__attribute__((address_space(3))) void*)(sA + ebase), 16, 0, 0);
      __builtin_amdgcn_global_load_lds(
          (const __attribute__((address_space(1))) void*)(Bt + (size_t)(n0 + row) * K + k0 + kk),
          (__attribute__((address_space(3))) void*)(sB + ebase), 16, 0, 0);
    }
    __syncthreads();

    short8 af[4][2], bfr[4][2];
    #pragma unroll
    for (int ks = 0; ks < 2; ++ks) {
      #pragma unroll
      for (int i = 0; i < 4; ++i)
        af[i][ks] = *reinterpret_cast<const short8*>(
            sA + (wm + i * 16 + (lane & 15)) * BK + ks * 32 + (lane >> 4) * 8);
      #pragma unroll
      for (int j = 0; j < 4; ++j)
        bfr[j][ks] = *reinterpret_cast<const short8*>(
            sB + (wn + j * 16 + (lane & 15)) * BK + ks * 32 + (lane >> 4) * 8);
    }
    #pragma unroll
    for (int ks = 0; ks < 2; ++ks)
      #pragma unroll
      for (int i = 0; i < 4; ++i)
        #pragma unroll
        for (int j = 0; j < 4; ++j)
          acc[i][j] = __builtin_amdgcn_mfma_f32_16x16x32_bf16(af[i][ks], bfr[j][ks], acc[i][j], 0, 0, 0);
    __syncthreads();
  }

  #pragma unroll
  for (int i = 0; i < 4; ++i)
    #pragma unroll
    for (int j = 0; j < 4; ++j)
      #pragma unroll
      for (int r = 0; r < 4; ++r)
        C[(size_t)(m0 + wm + i * 16 + ((lane >> 4) << 2) + r) * N + n0 + wn + j * 16 + (lane & 15)] = acc[i][j][r];
}

// ---------------------------------------------------------------------------
extern "C" void kernel_launch(void* const* d_in, const int* in_sizes, int n_in,
                              void* d_out, int out_size, void* d_ws, size_t ws_size,
                              hipStream_t stream) {
  const float* x   = (const float*)d_in[0];
  const float* wgt = (const float*)d_in[1];
  const float* lut = (const float*)d_in[2];
  float* out = (float*)d_out;

  const size_t statsBytes = 4 * IN_DIM * sizeof(float);            // 64 KiB
  const size_t qBytes     = (size_t)T_DIM * IN_DIM * 2;            // 32 MiB
  const size_t wtBytes    = (size_t)N_DIM * IN_DIM * 2;            // 32 MiB
  if (ws_size < statsBytes + qBytes + wtBytes) return;

  float* stats = (float*)d_ws;
  __hip_bfloat16* q  = (__hip_bfloat16*)((char*)d_ws + 65536);
  __hip_bfloat16* wt = (__hip_bfloat16*)((char*)d_ws + 65536 + qBytes);
  // cand (4 MiB) aliases the q region: consumed by stats_merge BEFORE
  // quant_kernel writes q (stream-ordered), so the overlap is safe.
  uint32_t* cand = (uint32_t*)q;

  stats_part <<<dim3(IN_DIM / 256, GROUPS), 256, 0, stream>>>(x, cand);
  stats_merge<<<dim3(IN_DIM / 256),         256, 0, stream>>>(cand, stats);
  quant_kernel<<<dim3((T_DIM * IN_DIM / 4) / 256), 256, 0, stream>>>(x, stats, lut, q);
  wt_kernel<<<dim3(N_DIM / 64, IN_DIM / 64), 256, 0, stream>>>(wgt, wt);
  gemm_kernel<<<dim3(N_DIM / 128, T_DIM / 128), 256, 0, stream>>>(q, wt, out);
}

// Round 6
// 315.585 us; speedup vs baseline: 1.2404x; 1.2404x over previous
//
#include <hip/hip_runtime.h>
#include <hip/hip_bf16.h>
#include <stdint.h>
#include <math.h>

#define T_DIM 4096   // rows of x2 (2*2048)
#define IN_DIM 4096  // inner dim
#define N_DIM 4096   // output dim
#define GROUPS 32    // row-groups for stats partial reduction
#define ROWS_PG (T_DIM / GROUPS)   // 128

typedef __attribute__((ext_vector_type(8))) short short8;
typedef __attribute__((ext_vector_type(4))) short short4v;
typedef __attribute__((ext_vector_type(4))) float f32x4;

__device__ __forceinline__ uint32_t umin32(uint32_t a, uint32_t b){ return a < b ? a : b; }
__device__ __forceinline__ uint32_t umax32(uint32_t a, uint32_t b){ return a > b ? a : b; }

__device__ __forceinline__ unsigned short bf16bits(float f) {
  __hip_bfloat16 h = __float2bfloat16(f);
  return *reinterpret_cast<unsigned short*>(&h);
}

// monotone float->uint key (ascending key order == ascending float order)
__device__ __forceinline__ uint32_t f2key(float f) {
  uint32_t u = __float_as_uint(f);
  return (u & 0x80000000u) ? ~u : (u | 0x80000000u);
}
__device__ __forceinline__ float key2f(uint32_t k) {
  uint32_t u = (k & 0x80000000u) ? (k ^ 0x80000000u) : ~k;
  return __uint_as_float(u);
}

// maintain sorted bottom-4 (b0<=b1<=b2<=b3)
__device__ __forceinline__ void ins_bot(uint32_t& b0, uint32_t& b1, uint32_t& b2, uint32_t& b3, uint32_t v) {
  b3 = umin32(b3, v);
  uint32_t lo, hi;
  lo = umin32(b2, b3); hi = umax32(b2, b3); b2 = lo; b3 = hi;
  lo = umin32(b1, b2); hi = umax32(b1, b2); b1 = lo; b2 = hi;
  lo = umin32(b0, b1); hi = umax32(b0, b1); b0 = lo; b1 = hi;
}
// maintain sorted top-4 (t0>=t1>=t2>=t3)
__device__ __forceinline__ void ins_top(uint32_t& t0, uint32_t& t1, uint32_t& t2, uint32_t& t3, uint32_t v) {
  t3 = umax32(t3, v);
  uint32_t lo, hi;
  hi = umax32(t2, t3); lo = umin32(t2, t3); t2 = hi; t3 = lo;
  hi = umax32(t1, t2); lo = umin32(t1, t2); t1 = hi; t2 = lo;
  hi = umax32(t0, t1); lo = umin32(t0, t1); t0 = hi; t1 = lo;
}

// ---------------------------------------------------------------------------
// K1a: partial per-column bottom-4/top-4 over a 128-row group.
// Thread owns one column -> every global load is wave-coalesced (256B/wave).
// ---------------------------------------------------------------------------
__global__ __launch_bounds__(256) void stats_part(const float* __restrict__ x,
                                                  uint32_t* __restrict__ cand) {
  const int c = blockIdx.x * 256 + threadIdx.x;
  const int g = blockIdx.y;
  const float* xp = x + (size_t)g * ROWS_PG * IN_DIM + c;

  uint32_t b0 = 0xFFFFFFFFu, b1 = 0xFFFFFFFFu, b2 = 0xFFFFFFFFu, b3 = 0xFFFFFFFFu;
  uint32_t t0 = 0u, t1 = 0u, t2 = 0u, t3 = 0u;
  #pragma unroll 8
  for (int r = 0; r < ROWS_PG; ++r) {
    const uint32_t v = f2key(xp[(size_t)r * IN_DIM]);
    ins_bot(b0, b1, b2, b3, v);
    ins_top(t0, t1, t2, t3, v);
  }
  const size_t base = (size_t)g * IN_DIM + c;
  const size_t stride = (size_t)GROUPS * IN_DIM;
  cand[0 * stride + base] = b0;
  cand[1 * stride + base] = b1;
  cand[2 * stride + base] = b2;
  cand[3 * stride + base] = b3;
  cand[4 * stride + base] = t0;
  cand[5 * stride + base] = t1;
  cand[6 * stride + base] = t2;
  cand[7 * stride + base] = t3;
}

// ---------------------------------------------------------------------------
// K1b: merge GROUPS candidate quadruples per column -> stats.
// s[2]=b2, s[3]=b3, s[4092]=t3, s[4093]=t2; median is dead code (always
// strictly inside (lower,upper)), so masked min/max = s[3]/s[4092] exactly.
// ---------------------------------------------------------------------------
__global__ __launch_bounds__(256) void stats_merge(const uint32_t* __restrict__ cand,
                                                   float* __restrict__ stats) {
  const int c = blockIdx.x * 256 + threadIdx.x;
  const size_t stride = (size_t)GROUPS * IN_DIM;

  uint32_t b0 = 0xFFFFFFFFu, b1 = 0xFFFFFFFFu, b2 = 0xFFFFFFFFu, b3 = 0xFFFFFFFFu;
  uint32_t t0 = 0u, t1 = 0u, t2 = 0u, t3 = 0u;
  #pragma unroll 4
  for (int g = 0; g < GROUPS; ++g) {
    const size_t base = (size_t)g * IN_DIM + c;
    const uint32_t cb0 = cand[0 * stride + base];
    const uint32_t cb1 = cand[1 * stride + base];
    const uint32_t cb2 = cand[2 * stride + base];
    const uint32_t cb3 = cand[3 * stride + base];
    const uint32_t ct0 = cand[4 * stride + base];
    const uint32_t ct1 = cand[5 * stride + base];
    const uint32_t ct2 = cand[6 * stride + base];
    const uint32_t ct3 = cand[7 * stride + base];
    ins_bot(b0, b1, b2, b3, cb0); ins_bot(b0, b1, b2, b3, cb1);
    ins_bot(b0, b1, b2, b3, cb2); ins_bot(b0, b1, b2, b3, cb3);
    ins_top(t0, t1, t2, t3, ct0); ins_top(t0, t1, t2, t3, ct1);
    ins_top(t0, t1, t2, t3, ct2); ins_top(t0, t1, t2, t3, ct3);
  }

  const float s2 = key2f(b2), s3 = key2f(b3);
  const float s4092 = key2f(t3), s4093 = key2f(t2);
  const float lowerF = s2 + 0.0475f * (s3 - s2);          // pos 0.0005*4095
  const float upperF = s4092 + 0.9525f * (s4093 - s4092); // pos 0.9995*4095
  const float minval = s3, maxval = s4092;                // exact masked min/max
  stats[0 * IN_DIM + c] = lowerF;
  stats[1 * IN_DIM + c] = upperF;
  stats[2 * IN_DIM + c] = (maxval + minval) * 0.5f;
  stats[3 * IN_DIM + c] = (maxval - minval) * 0.5f;
}

// ---------------------------------------------------------------------------
// K2: quantize x -> q (bf16). Row-major vectorized: float4 in, 4x bf16 out.
// ---------------------------------------------------------------------------
__global__ __launch_bounds__(256) void quant_kernel(const float* __restrict__ x,
                                                    const float* __restrict__ stats,
                                                    const float* __restrict__ lut,
                                                    __hip_bfloat16* __restrict__ q) {
  const size_t e0 = ((size_t)blockIdx.x * 256 + threadIdx.x) * 4;
  const int c = (int)(e0 & (IN_DIM - 1));   // 4 consecutive cols, no row wrap

  float lutv[16];
  #pragma unroll
  for (int j = 0; j < 16; ++j) lutv[j] = lut[j];
  float mid[15];
  #pragma unroll
  for (int j = 0; j < 15; ++j) mid[j] = 0.5f * (lutv[j] + lutv[j + 1]);

  const float4 xv4  = *reinterpret_cast<const float4*>(x + e0);
  const float4 lo4  = *reinterpret_cast<const float4*>(stats + 0 * IN_DIM + c);
  const float4 hi4  = *reinterpret_cast<const float4*>(stats + 1 * IN_DIM + c);
  const float4 off4 = *reinterpret_cast<const float4*>(stats + 2 * IN_DIM + c);
  const float4 rng4 = *reinterpret_cast<const float4*>(stats + 3 * IN_DIM + c);

  const float xs[4]  = {xv4.x, xv4.y, xv4.z, xv4.w};
  const float los[4] = {lo4.x, lo4.y, lo4.z, lo4.w};
  const float his[4] = {hi4.x, hi4.y, hi4.z, hi4.w};
  const float ofs[4] = {off4.x, off4.y, off4.z, off4.w};
  const float rgs[4] = {rng4.x, rng4.y, rng4.z, rng4.w};

  short4v outv;
  #pragma unroll
  for (int j = 0; j < 4; ++j) {
    const float xv = xs[j];
    const bool msk = (xv <= los[j]) || (xv >= his[j]);
    const float xc = xv - ofs[j];
    const float s = xc / rgs[j];
    float p = lutv[0];
    #pragma unroll
    for (int j2 = 0; j2 < 15; ++j2) p = (s > mid[j2]) ? lutv[j2 + 1] : p;
    float qv = msk ? (xc + ofs[j]) : (p * rgs[j] + ofs[j]);
    if (!isfinite(qv)) qv = 0.0f;
    outv[j] = (short)bf16bits(qv);
  }
  *reinterpret_cast<short4v*>((short*)q + e0) = outv;   // 8 B aligned store
}

// ---------------------------------------------------------------------------
// K2b: W (K x N, f32) -> Wt (N x K, bf16). float4 loads, bf16 LDS tile
// (padded: 2-way banks only), 8 B vector stores.
// ---------------------------------------------------------------------------
__global__ __launch_bounds__(256) void wt_kernel(const float* __restrict__ wsrc,
                                                 __hip_bfloat16* __restrict__ wt) {
  __shared__ unsigned short tile[64][68];  // bf16, +4 pad keeps 8B-aligned rows
  const int n0 = blockIdx.x * 64, k0 = blockIdx.y * 64;
  const int lr = threadIdx.x >> 4;   // 0..15
  const int lc = threadIdx.x & 15;   // 0..15

  #pragma unroll
  for (int it = 0; it < 4; ++it) {
    const int krow = it * 16 + lr;
    const float4 v = *reinterpret_cast<const float4*>(wsrc + (size_t)(k0 + krow) * N_DIM + n0 + lc * 4);
    short4v b;
    b[0] = (short)bf16bits(v.x);
    b[1] = (short)bf16bits(v.y);
    b[2] = (short)bf16bits(v.z);
    b[3] = (short)bf16bits(v.w);
    *reinterpret_cast<short4v*>(&tile[krow][lc * 4]) = b;
  }
  __syncthreads();
  #pragma unroll
  for (int it = 0; it < 4; ++it) {
    const int nrow = it * 16 + lr;
    short4v o;
    #pragma unroll
    for (int i = 0; i < 4; ++i) o[i] = (short)tile[lc * 4 + i][nrow];
    *reinterpret_cast<short4v*>((short*)wt + (size_t)(n0 + nrow) * IN_DIM + k0 + lc * 4) = o;
  }
}

// ---------------------------------------------------------------------------
// K3: C = q(M x K) @ Wt^T (Wt is N x K). 256x256 tile, BK=64, 8 waves (2Mx4N),
// double-buffered LDS (128 KiB), counted vmcnt(8), raw s_barrier (no drain).
// LDS XOR-swizzle via pre-swizzled GLOBAL source (linear glds dest) + same
// XOR on ds_read (both-sides rule). Fragment/C-write math identical to the
// verified 128-tile kernel.
// ---------------------------------------------------------------------------
#define BM 256
#define BKS 64
#define NT (IN_DIM / BKS)   // 64

__global__ __launch_bounds__(512, 2) void gemm_kernel(const __hip_bfloat16* __restrict__ A,
                                                      const __hip_bfloat16* __restrict__ Bt,
                                                      float* __restrict__ C) {
  constexpr int K = IN_DIM, N = N_DIM;
  // [buf][0=A,1=B][256*64 shorts] -> 2*2*32KB = 128 KiB
  __shared__ short lds[2][2][BM * BKS];
  const int tid = threadIdx.x, lane = tid & 63, w = tid >> 6;
  const int m0 = blockIdx.y * BM, n0 = blockIdx.x * BM;
  const int wm = (w >> 2) * 128;   // wave row-block (2 waves in M)
  const int wn = (w & 3) * 64;     // wave col-block (4 waves in N)

  // staging: linear LDS (glds needs contiguous dest), inverse-swizzled source.
  // linear slot (shorts) L = ra*4096 + tid*8 -> row = ra*64 + (tid>>3),
  // col = (tid&7)*8; source col = col ^ ((row&7)<<3).
  const int srow = tid >> 3;
  const int kksrc = (((tid & 7) ^ ((tid >> 3) & 7)) << 3);

  f32x4 acc[8][4] = {};

  auto stage = [&](int buf, int t) {
    const int k0 = t * BKS;
    #pragma unroll
    for (int ra = 0; ra < 4; ++ra) {
      const int row = ra * 64 + srow;
      const int ebase = ra * 4096 + w * 512;   // shorts; wave-uniform base
      __builtin_amdgcn_global_load_lds(
        (const __attribute__((address_space(1))) void*)(A + (size_t)(m0 + row) * K + k0 + kksrc),
        (__attribute__((address_space(3))) void*)(&lds[buf][0][ebase]), 16, 0, 0);
    }
    #pragma unroll
    for (int ra = 0; ra < 4; ++ra) {
      const int row = ra * 64 + srow;
      const int ebase = ra * 4096 + w * 512;
      __builtin_amdgcn_global_load_lds(
        (const __attribute__((address_space(1))) void*)(Bt + (size_t)(n0 + row) * K + k0 + kksrc),
        (__attribute__((address_space(3))) void*)(&lds[buf][1][ebase]), 16, 0, 0);
    }
  };

  auto compute = [&](int buf) {
    #pragma unroll
    for (int s = 0; s < 2; ++s) {
      short8 a[8], b[4];
      #pragma unroll
      for (int i = 0; i < 8; ++i) {
        const int row = wm + i * 16 + (lane & 15);
        const int kk = (s * 32 + (lane >> 4) * 8) ^ ((row & 7) << 3);
        a[i] = *reinterpret_cast<const short8*>(&lds[buf][0][row * BKS + kk]);
      }
      #pragma unroll
      for (int j = 0; j < 4; ++j) {
        const int row = wn + j * 16 + (lane & 15);
        const int kk = (s * 32 + (lane >> 4) * 8) ^ ((row & 7) << 3);
        b[j] = *reinterpret_cast<const short8*>(&lds[buf][1][row * BKS + kk]);
      }
      __builtin_amdgcn_s_setprio(1);
      #pragma unroll
      for (int i = 0; i < 8; ++i)
        #pragma unroll
        for (int j = 0; j < 4; ++j)
          acc[i][j] = __builtin_amdgcn_mfma_f32_16x16x32_bf16(a[i], b[j], acc[i][j], 0, 0, 0);
      __builtin_amdgcn_s_setprio(0);
    }
  };

  // prologue: tiles 0 and 1 in flight; wait tile 0 (8 newest may remain)
  stage(0, 0);
  stage(1, 1);
  asm volatile("s_waitcnt vmcnt(8)" ::: "memory");
  __builtin_amdgcn_sched_barrier(0);
  __builtin_amdgcn_s_barrier();
  __builtin_amdgcn_sched_barrier(0);

  int cur = 0;
  for (int t = 0; t < NT; ++t) {
    compute(cur);
    if (t < NT - 1) {
      asm volatile("s_waitcnt lgkmcnt(0)" ::: "memory");  // reads of buf[cur] done
      __builtin_amdgcn_sched_barrier(0);
      __builtin_amdgcn_s_barrier();                        // B1: safe to overwrite
      __builtin_amdgcn_sched_barrier(0);
      if (t + 2 < NT) {
        stage(cur, t + 2);                                 // 8 loads, stay in flight
        asm volatile("s_waitcnt vmcnt(8)" ::: "memory");   // tile t+1 landed
      } else {
        asm volatile("s_waitcnt vmcnt(0)" ::: "memory");   // drain last tile
      }
      __builtin_amdgcn_sched_barrier(0);
      __builtin_amdgcn_s_barrier();                        // B2: buf[cur^1] ready
      __builtin_amdgcn_sched_barrier(0);
    }
    cur ^= 1;
  }

  #pragma unroll
  for (int i = 0; i < 8; ++i)
    #pragma unroll
    for (int j = 0; j < 4; ++j)
      #pragma unroll
      for (int r = 0; r < 4; ++r)
        C[(size_t)(m0 + wm + i * 16 + ((lane >> 4) << 2) + r) * N + n0 + wn + j * 16 + (lane & 15)] = acc[i][j][r];
}

// ---------------------------------------------------------------------------
extern "C" void kernel_launch(void* const* d_in, const int* in_sizes, int n_in,
                              void* d_out, int out_size, void* d_ws, size_t ws_size,
                              hipStream_t stream) {
  const float* x   = (const float*)d_in[0];
  const float* wgt = (const float*)d_in[1];
  const float* lut = (const float*)d_in[2];
  float* out = (float*)d_out;

  const size_t statsBytes = 4 * IN_DIM * sizeof(float);            // 64 KiB
  const size_t qBytes     = (size_t)T_DIM * IN_DIM * 2;            // 32 MiB
  const size_t wtBytes    = (size_t)N_DIM * IN_DIM * 2;            // 32 MiB
  if (ws_size < statsBytes + qBytes + wtBytes) return;

  float* stats = (float*)d_ws;
  __hip_bfloat16* q  = (__hip_bfloat16*)((char*)d_ws + 65536);
  __hip_bfloat16* wt = (__hip_bfloat16*)((char*)d_ws + 65536 + qBytes);
  // cand (4 MiB) aliases the q region: consumed by stats_merge BEFORE
  // quant_kernel writes q (stream-ordered), so the overlap is safe.
  uint32_t* cand = (uint32_t*)q;

  stats_part <<<dim3(IN_DIM / 256, GROUPS), 256, 0, stream>>>(x, cand);
  stats_merge<<<dim3(IN_DIM / 256),         256, 0, stream>>>(cand, stats);
  quant_kernel<<<dim3((T_DIM * IN_DIM / 4) / 256), 256, 0, stream>>>(x, stats, lut, q);
  wt_kernel<<<dim3(N_DIM / 64, IN_DIM / 64), 256, 0, stream>>>(wgt, wt);
  gemm_kernel<<<dim3(N_DIM / BM, T_DIM / BM), 512, 0, stream>>>(q, wt, out);
}